// Round 1
// 180.114 us; speedup vs baseline: 1.1252x; 1.1252x over previous
//
#include <hip/hip_runtime.h>
#include <math.h>

// Problem: B=512 queries, N=131072 bank items, D=256, 64 bags, 96x96 grid,
// hit iff same bag && 0 < dx^2+dy^2 < 4 (the 8-neighborhood), temp 0.2.
//
// Mask-first algorithm: expected hits = 512*131072*(1/64)*(8/9216) ~= 900
// device-wide, so we touch only ~900 of the 131072 memory rows (~0.9 MB of
// the 134 MB array). Coords are small ints -> integer d2 test is bit-exact
// vs the reference's fp32 squared-distance expansion.
//
// Round-4 structure: same single fused kernel, but the hit dot-products are
// now WAVE-PARALLEL instead of per-lane-serial. Previously each hit lane ran
// a 64-iteration float4 loop over a cold memory row (~8 serialized HBM
// round-trips, 1/64 lanes active under the divergent branch). Now hits are
// compacted into an LDS worklist; after a barrier each wave takes one hit:
// 64 lanes x 1 float4 = the full 256-float row in ONE coalesced 1KB
// transaction for q and for m, then a 6-level butterfly reduce.
#define NBAGS  64
#define BAGCAP 40      // max queries/bag; binomial(512,1/64) max ~20; 40 is >8 sigma
#define TBL    (BAGCAP * NBAGS)
#define D4     64      // D/4 float4s per feature row
#define HITCAP 64      // hits/block ~ Poisson(1.8); 64 is absurd overkill; fallback below

__global__ void __launch_bounds__(256)
k_fused(const float* __restrict__ q,
        const float* __restrict__ memory,
        const int* __restrict__ bag_idx,    // [B] query bag
        const int* __restrict__ x_coord,    // [B]
        const int* __restrict__ y_coord,    // [B]
        const int* __restrict__ bag_idxs,   // [N] bank bag
        const int* __restrict__ x_coords,   // [N]
        const int* __restrict__ y_coords,   // [N]
        float* __restrict__ out,            // [B], pre-zeroed by memset
        int B, int N)
{
    __shared__ int s_cnt[NBAGS];
    __shared__ int s_tbl[TBL];   // transposed: tbl[slot*64+bag] -> bank=bag%32,
                                 // readers at fixed slot alias <=2-way (free)
    __shared__ int s_nhit;
    __shared__ int s_hit[HITCAP]; // packed (j << 9) | query_idx  (17b + 9b)

    int tid = threadIdx.x;
    if (tid < NBAGS) s_cnt[tid] = 0;
    if (tid == NBAGS) s_nhit = 0;
    __syncthreads();

    // Build the bag->queries table from raw metadata (6 KB, L2-hot).
    // entry packing: (query_idx << 14) | (x << 7) | y
    for (int i = tid; i < B; i += 256) {
        int bag  = bag_idx[i];
        int slot = atomicAdd(&s_cnt[bag], 1);
        if (slot < BAGCAP)
            s_tbl[slot * NBAGS + bag] = (i << 14) | (x_coord[i] << 7) | y_coord[i];
    }
    __syncthreads();

    const float4* q4 = (const float4*)q;
    const float4* m4 = (const float4*)memory;

    int j = blockIdx.x * 256 + tid;
    if (j < N) {
        int jb = bag_idxs[j];
        int jx = x_coords[j];
        int jy = y_coords[j];
        int n  = min(s_cnt[jb], BAGCAP);   // ~8 avg

        for (int i = 0; i < n; ++i) {
            int e  = s_tbl[i * NBAGS + jb];
            int dx = ((e >> 7) & 127) - jx;
            int dy = (e & 127) - jy;
            int d2 = dx * dx + dy * dy;
            if (d2 > 0 && d2 < 4) {        // exact vs reference's fp32 test
                int b    = e >> 14;
                int slot = atomicAdd(&s_nhit, 1);
                if (slot < HITCAP) {
                    s_hit[slot] = (j << 9) | b;
                } else {
                    // statistically unreachable fallback: serial dot, as round-3
                    const float4* qr = q4 + b * D4;
                    const float4* mr = m4 + (long)j * D4;
                    float qq = 0.0f, qm = 0.0f;
                    #pragma unroll 8
                    for (int k = 0; k < D4; ++k) {
                        float4 a = qr[k];
                        float4 m = mr[k];
                        qq += a.x * a.x + a.y * a.y + a.z * a.z + a.w * a.w;
                        qm += a.x * m.x + a.y * m.y + a.z * m.z + a.w * m.w;
                    }
                    atomicAdd(&out[b], expf(qm / sqrtf(qq) * 5.0f));
                }
            }
        }
    }
    __syncthreads();

    // Wave-parallel dot products: one hit per wave, 64 lanes x 1 float4
    // covers the full D=256 row. q rows are L2/L3-hot (512 KB total);
    // m rows are one cold, perfectly-coalesced 1KB fetch each.
    int nh   = min(s_nhit, HITCAP);
    int wave = tid >> 6;
    int lane = tid & 63;
    for (int h = wave; h < nh; h += 4) {
        int e  = s_hit[h];
        int b  = e & 511;
        int jj = e >> 9;
        float4 a = q4[b * D4 + lane];
        float4 m = m4[(long)jj * D4 + lane];
        float qq = a.x * a.x + a.y * a.y + a.z * a.z + a.w * a.w;
        float qm = a.x * m.x + a.y * m.y + a.z * m.z + a.w * m.w;
        #pragma unroll
        for (int mask = 32; mask >= 1; mask >>= 1) {
            qq += __shfl_xor(qq, mask, 64);
            qm += __shfl_xor(qm, mask, 64);
        }
        if (lane == 0)
            atomicAdd(&out[b], expf(qm / sqrtf(qq) * 5.0f));  // exp(l / 0.2)
    }
}

extern "C" void kernel_launch(void* const* d_in, const int* in_sizes, int n_in,
                              void* d_out, int out_size, void* d_ws, size_t ws_size,
                              hipStream_t stream)
{
    const float* q        = (const float*)d_in[0];
    const float* memory   = (const float*)d_in[1];
    const int*   bag_idx  = (const int*)d_in[2];
    const int*   x_coord  = (const int*)d_in[3];
    const int*   y_coord  = (const int*)d_in[4];
    const int*   bag_idxs = (const int*)d_in[5];
    const int*   x_coords = (const int*)d_in[6];
    const int*   y_coords = (const int*)d_in[7];
    float*       out      = (float*)d_out;

    int B = in_sizes[2];   // 512
    int N = in_sizes[5];   // 131072

    // d_out is poisoned to 0xAA before every timed call; zero it via a
    // capturable async memset (becomes a graph memset node).
    hipMemsetAsync(out, 0, (size_t)out_size * sizeof(float), stream);

    int threads = 256;
    int blocks  = (N + threads - 1) / threads;  // 512
    k_fused<<<blocks, threads, 0, stream>>>(q, memory, bag_idx, x_coord, y_coord,
                                            bag_idxs, x_coords, y_coords,
                                            out, B, N);
}